// Round 1
// baseline (328.722 us; speedup 1.0000x reference)
//
#include <hip/hip_runtime.h>

#define DIM 33
#define DIM2 (DIM * DIM)
#define NLUT (DIM * DIM * DIM)   // 35937

// Repack channel-planar LUT (3 x 35937 floats) into AoS float4 (r,g,b,0)
// so one 16B gather fetches all 3 channels of a corner.
__global__ void repack_lut_kernel(const float* __restrict__ lut,
                                  float4* __restrict__ lut4) {
    int i = blockIdx.x * blockDim.x + threadIdx.x;
    if (i < NLUT) {
        lut4[i] = make_float4(lut[i], lut[NLUT + i], lut[2 * NLUT + i], 0.0f);
    }
}

__device__ __forceinline__ float4 lerp4(const float4 a, const float4 b, const float t) {
    return make_float4(fmaf(t, b.x - a.x, a.x),
                       fmaf(t, b.y - a.y, a.y),
                       fmaf(t, b.z - a.z, a.z),
                       0.0f);
}

// Each thread handles 4 consecutive pixels (float4 per channel plane).
// Layout: x/out are (B, 3, H, W); plane stride = H*W floats.
__global__ __launch_bounds__(256) void lut3d_apply_kernel(
    const float* __restrict__ x, const float4* __restrict__ lut4,
    float* __restrict__ out, int n4) {
    constexpr int HW  = 1024 * 1024;
    constexpr int HW4 = HW / 4;

    int t = blockIdx.x * blockDim.x + threadIdx.x;
    if (t >= n4) return;
    int b  = t >> 18;            // t / HW4   (HW4 == 2^18)
    int hw = t & (HW4 - 1);      // t % HW4

    const float4* xp = reinterpret_cast<const float4*>(x + (size_t)b * 3 * HW) + hw;
    float4 r4 = xp[0];
    float4 g4 = xp[HW4];
    float4 b4 = xp[2 * HW4];

    float4 or4, og4, ob4;
    const float inv_bin = 32.0f / 1.000001f;

#pragma unroll
    for (int k = 0; k < 4; ++k) {
        float r = (&r4.x)[k];
        float g = (&g4.x)[k];
        float bb = (&b4.x)[k];

        float rs = r * inv_bin;
        float gs = g * inv_bin;
        float bs = bb * inv_bin;
        float rf = floorf(rs), gf = floorf(gs), bf = floorf(bs);
        int rid = (int)rf, gid = (int)gf, bid = (int)bf;
        float rd = rs - rf, gd = gs - gf, bd = bs - bf;

        int idx = rid + gid * DIM + bid * DIM2;

        float4 c000 = lut4[idx];
        float4 c100 = lut4[idx + 1];
        float4 c010 = lut4[idx + DIM];
        float4 c110 = lut4[idx + DIM + 1];
        float4 c001 = lut4[idx + DIM2];
        float4 c101 = lut4[idx + DIM2 + 1];
        float4 c011 = lut4[idx + DIM2 + DIM];
        float4 c111 = lut4[idx + DIM2 + DIM + 1];

        float4 a00 = lerp4(c000, c100, rd);
        float4 a10 = lerp4(c010, c110, rd);
        float4 a01 = lerp4(c001, c101, rd);
        float4 a11 = lerp4(c011, c111, rd);
        float4 m0  = lerp4(a00, a10, gd);
        float4 m1  = lerp4(a01, a11, gd);
        float4 res = lerp4(m0, m1, bd);

        (&or4.x)[k] = res.x;
        (&og4.x)[k] = res.y;
        (&ob4.x)[k] = res.z;
    }

    float4* op = reinterpret_cast<float4*>(out + (size_t)b * 3 * HW) + hw;
    op[0]       = or4;
    op[HW4]     = og4;
    op[2 * HW4] = ob4;
}

// Fallback (no workspace): gather scalars directly from the planar LUT.
__global__ __launch_bounds__(256) void lut3d_apply_direct_kernel(
    const float* __restrict__ x, const float* __restrict__ lut,
    float* __restrict__ out, int n4) {
    constexpr int HW  = 1024 * 1024;
    constexpr int HW4 = HW / 4;

    int t = blockIdx.x * blockDim.x + threadIdx.x;
    if (t >= n4) return;
    int b  = t >> 18;
    int hw = t & (HW4 - 1);

    const float4* xp = reinterpret_cast<const float4*>(x + (size_t)b * 3 * HW) + hw;
    float4 r4 = xp[0];
    float4 g4 = xp[HW4];
    float4 b4 = xp[2 * HW4];

    float4 or4, og4, ob4;
    const float inv_bin = 32.0f / 1.000001f;

#pragma unroll
    for (int k = 0; k < 4; ++k) {
        float r = (&r4.x)[k];
        float g = (&g4.x)[k];
        float bb = (&b4.x)[k];

        float rs = r * inv_bin;
        float gs = g * inv_bin;
        float bs = bb * inv_bin;
        float rf = floorf(rs), gf = floorf(gs), bf = floorf(bs);
        int rid = (int)rf, gid = (int)gf, bid = (int)bf;
        float rd = rs - rf, gd = gs - gf, bd = bs - bf;

        int idx = rid + gid * DIM + bid * DIM2;

        float outc[3];
#pragma unroll
        for (int c = 0; c < 3; ++c) {
            const float* lc = lut + (size_t)c * NLUT;
            float c000 = lc[idx];
            float c100 = lc[idx + 1];
            float c010 = lc[idx + DIM];
            float c110 = lc[idx + DIM + 1];
            float c001 = lc[idx + DIM2];
            float c101 = lc[idx + DIM2 + 1];
            float c011 = lc[idx + DIM2 + DIM];
            float c111 = lc[idx + DIM2 + DIM + 1];
            float a00 = fmaf(rd, c100 - c000, c000);
            float a10 = fmaf(rd, c110 - c010, c010);
            float a01 = fmaf(rd, c101 - c001, c001);
            float a11 = fmaf(rd, c111 - c011, c011);
            float m0  = fmaf(gd, a10 - a00, a00);
            float m1  = fmaf(gd, a11 - a01, a01);
            outc[c]   = fmaf(bd, m1 - m0, m0);
        }
        (&or4.x)[k] = outc[0];
        (&og4.x)[k] = outc[1];
        (&ob4.x)[k] = outc[2];
    }

    float4* op = reinterpret_cast<float4*>(out + (size_t)b * 3 * HW) + hw;
    op[0]       = or4;
    op[HW4]     = og4;
    op[2 * HW4] = ob4;
}

extern "C" void kernel_launch(void* const* d_in, const int* in_sizes, int n_in,
                              void* d_out, int out_size, void* d_ws, size_t ws_size,
                              hipStream_t stream) {
    const float* x   = (const float*)d_in[0];
    const float* lut = (const float*)d_in[1];
    float* out       = (float*)d_out;

    constexpr int B  = 16;
    constexpr int HW = 1024 * 1024;
    const int n4 = B * (HW / 4);               // 4,194,304 thread-groups
    const int blocks = (n4 + 255) / 256;       // 16384 blocks

    const size_t lut4_bytes = (size_t)NLUT * sizeof(float4);  // 575 KB

    if (ws_size >= lut4_bytes) {
        float4* lut4 = (float4*)d_ws;
        repack_lut_kernel<<<(NLUT + 255) / 256, 256, 0, stream>>>(lut, lut4);
        lut3d_apply_kernel<<<blocks, 256, 0, stream>>>(x, lut4, out, n4);
    } else {
        lut3d_apply_direct_kernel<<<blocks, 256, 0, stream>>>(x, lut, out, n4);
    }
}

// Round 3
// 290.889 us; speedup vs baseline: 1.1301x; 1.1301x over previous
//
#include <hip/hip_runtime.h>
#include <hip/hip_fp16.h>

#define DIM 33
#define DIM2 (DIM * DIM)
#define NLUT (DIM * DIM * DIM)   // 35937

typedef float  v4f  __attribute__((ext_vector_type(4)));
typedef unsigned int v4u __attribute__((ext_vector_type(4)));

// Repack channel-planar f32 LUT (3 x 35937) into fp16 r-pair entries:
// pairs[i] = { h(r[i]), h(g[i]), h(b[i]), 0, h(r[i+1]), h(g[i+1]), h(b[i+1]), 0 } (16 B)
// One 16B gather then yields BOTH r-corners of one (g,b) corner combo.
__global__ void repack_lut_pairs_kernel(const float* __restrict__ lut,
                                        v4u* __restrict__ pairs) {
    int i = blockIdx.x * blockDim.x + threadIdx.x;
    if (i >= NLUT) return;
    int j = (i + 1 < NLUT) ? i + 1 : i;
    unsigned r0 = __half_as_ushort(__float2half(lut[i]));
    unsigned g0 = __half_as_ushort(__float2half(lut[NLUT + i]));
    unsigned b0 = __half_as_ushort(__float2half(lut[2 * NLUT + i]));
    unsigned r1 = __half_as_ushort(__float2half(lut[j]));
    unsigned g1 = __half_as_ushort(__float2half(lut[NLUT + j]));
    unsigned b1 = __half_as_ushort(__float2half(lut[2 * NLUT + j]));
    v4u p;
    p.x = r0 | (g0 << 16);
    p.y = b0;                 // pad in high half
    p.z = r1 | (g1 << 16);
    p.w = b1;
    pairs[i] = p;
}

struct f3 { float x, y, z; };

// r-lerp one pair entry -> f3 (interpolated along r)
__device__ __forceinline__ f3 rlerp(const v4u p, const float rd) {
    unsigned px = p.x, py = p.y, pz = p.z, pw = p.w;
    float2 rg0 = __half22float2(*reinterpret_cast<const __half2*>(&px));
    float2 b0_ = __half22float2(*reinterpret_cast<const __half2*>(&py));
    float2 rg1 = __half22float2(*reinterpret_cast<const __half2*>(&pz));
    float2 b1_ = __half22float2(*reinterpret_cast<const __half2*>(&pw));
    f3 o;
    o.x = fmaf(rd, rg1.x - rg0.x, rg0.x);
    o.y = fmaf(rd, rg1.y - rg0.y, rg0.y);
    o.z = fmaf(rd, b1_.x - b0_.x, b0_.x);
    return o;
}

__device__ __forceinline__ f3 lerp3(const f3 a, const f3 b, const float t) {
    f3 o;
    o.x = fmaf(t, b.x - a.x, a.x);
    o.y = fmaf(t, b.y - a.y, a.y);
    o.z = fmaf(t, b.z - a.z, a.z);
    return o;
}

// Each thread: 4 consecutive pixels. Phase 1 computes all indices and issues
// all 16 gathers; phase 2 interpolates. x/out traffic is nontemporal so the
// LUT keeps L1/L2.
__global__ __launch_bounds__(256) void lut3d_apply_kernel(
    const float* __restrict__ x, const v4u* __restrict__ pairs,
    float* __restrict__ out, int n4) {
    constexpr int HW  = 1024 * 1024;
    constexpr int HW4 = HW / 4;

    int t = blockIdx.x * blockDim.x + threadIdx.x;
    if (t >= n4) return;
    int b  = t >> 18;            // t / HW4   (HW4 == 2^18)
    int hw = t & (HW4 - 1);      // t % HW4

    const v4f* xp = reinterpret_cast<const v4f*>(x + (size_t)b * 3 * HW) + hw;
    v4f r4 = __builtin_nontemporal_load(xp);
    v4f g4 = __builtin_nontemporal_load(xp + HW4);
    v4f b4 = __builtin_nontemporal_load(xp + 2 * HW4);

    const float inv_bin = 32.0f / 1.000001f;

    float rd[4], gd[4], bd[4];
    v4u P00[4], P10[4], P01[4], P11[4];

    // Phase 1: indices + issue all gathers
#pragma unroll
    for (int k = 0; k < 4; ++k) {
        float r  = r4[k];
        float g  = g4[k];
        float bb = b4[k];

        float rs = r * inv_bin;
        float gs = g * inv_bin;
        float bs = bb * inv_bin;
        float rf = floorf(rs), gf = floorf(gs), bf = floorf(bs);
        int rid = (int)rf, gid = (int)gf, bid = (int)bf;
        rd[k] = rs - rf;
        gd[k] = gs - gf;
        bd[k] = bs - bf;

        int idx = rid + gid * DIM + bid * DIM2;
        P00[k] = pairs[idx];
        P10[k] = pairs[idx + DIM];
        P01[k] = pairs[idx + DIM2];
        P11[k] = pairs[idx + DIM2 + DIM];
    }

    v4f or4, og4, ob4;

    // Phase 2: interpolate
#pragma unroll
    for (int k = 0; k < 4; ++k) {
        f3 a00 = rlerp(P00[k], rd[k]);   // (g=0,b=0) r-interp
        f3 a10 = rlerp(P10[k], rd[k]);   // (g=1,b=0)
        f3 a01 = rlerp(P01[k], rd[k]);   // (g=0,b=1)
        f3 a11 = rlerp(P11[k], rd[k]);   // (g=1,b=1)
        f3 m0  = lerp3(a00, a10, gd[k]);
        f3 m1  = lerp3(a01, a11, gd[k]);
        f3 res = lerp3(m0, m1, bd[k]);
        or4[k] = res.x;
        og4[k] = res.y;
        ob4[k] = res.z;
    }

    v4f* op = reinterpret_cast<v4f*>(out + (size_t)b * 3 * HW) + hw;
    __builtin_nontemporal_store(or4, op);
    __builtin_nontemporal_store(og4, op + HW4);
    __builtin_nontemporal_store(ob4, op + 2 * HW4);
}

extern "C" void kernel_launch(void* const* d_in, const int* in_sizes, int n_in,
                              void* d_out, int out_size, void* d_ws, size_t ws_size,
                              hipStream_t stream) {
    const float* x   = (const float*)d_in[0];
    const float* lut = (const float*)d_in[1];
    float* out       = (float*)d_out;

    constexpr int B  = 16;
    constexpr int HW = 1024 * 1024;
    const int n4 = B * (HW / 4);               // 4,194,304 threads
    const int blocks = (n4 + 255) / 256;       // 16384 blocks

    v4u* pairs = (v4u*)d_ws;                   // 575 KB, ws is preallocated
    repack_lut_pairs_kernel<<<(NLUT + 255) / 256, 256, 0, stream>>>(lut, pairs);
    lut3d_apply_kernel<<<blocks, 256, 0, stream>>>(x, pairs, out, n4);
}

// Round 4
// 233.653 us; speedup vs baseline: 1.4069x; 1.2450x over previous
//
#include <hip/hip_runtime.h>
#include <hip/hip_fp16.h>

#define DIM 33
#define DIM2 (DIM * DIM)
#define NLUT (DIM * DIM * DIM)     // 35937
#define NCELL (32 * 32 * 32)       // 32768 cells, 64 B each -> 2 MB

typedef float        v4f __attribute__((ext_vector_type(4)));
typedef unsigned int v4u __attribute__((ext_vector_type(4)));

__device__ __forceinline__ unsigned pack2h(float a, float b) {
    unsigned lo = __half_as_ushort(__float2half(a));
    unsigned hi = __half_as_ushort(__float2half(b));
    return lo | (hi << 16);
}

// Build the cell table: cell cid=(rid,gid,bid) holds its 8 corners as four
// 16B chunks (one per (dg,db) combo), each chunk an fp16 r-pair:
// { h(r0),h(g0) | h(b0),0 | h(r1),h(g1) | h(b1),0 }  where 0/1 = r-corner.
// One pixel's whole stencil = one 64B line.
__global__ void repack_cells_kernel(const float* __restrict__ lut,
                                    v4u* __restrict__ cells) {
    int cid = blockIdx.x * blockDim.x + threadIdx.x;
    if (cid >= NCELL) return;
    int rid = cid & 31;
    int gid = (cid >> 5) & 31;
    int bid = cid >> 10;
    int base = rid + gid * DIM + bid * DIM2;

    const float* Lr = lut;
    const float* Lg = lut + NLUT;
    const float* Lb = lut + 2 * NLUT;

#pragma unroll
    for (int db = 0; db < 2; ++db) {
#pragma unroll
        for (int dg = 0; dg < 2; ++dg) {
            int i0 = base + dg * DIM + db * DIM2;
            int i1 = i0 + 1;
            v4u p;
            p.x = pack2h(Lr[i0], Lg[i0]);
            p.y = pack2h(Lb[i0], 0.0f);
            p.z = pack2h(Lr[i1], Lg[i1]);
            p.w = pack2h(Lb[i1], 0.0f);
            cells[(size_t)cid * 4 + dg + db * 2] = p;
        }
    }
}

struct f3 { float x, y, z; };

// r-lerp one 16B chunk -> f3 (interpolated along r)
__device__ __forceinline__ f3 rlerp(const v4u p, const float rd) {
    unsigned px = p.x, py = p.y, pz = p.z, pw = p.w;
    float2 rg0 = __half22float2(*reinterpret_cast<const __half2*>(&px));
    float2 b0_ = __half22float2(*reinterpret_cast<const __half2*>(&py));
    float2 rg1 = __half22float2(*reinterpret_cast<const __half2*>(&pz));
    float2 b1_ = __half22float2(*reinterpret_cast<const __half2*>(&pw));
    f3 o;
    o.x = fmaf(rd, rg1.x - rg0.x, rg0.x);
    o.y = fmaf(rd, rg1.y - rg0.y, rg0.y);
    o.z = fmaf(rd, b1_.x - b0_.x, b0_.x);
    return o;
}

__device__ __forceinline__ f3 lerp3(const f3 a, const f3 b, const float t) {
    f3 o;
    o.x = fmaf(t, b.x - a.x, a.x);
    o.y = fmaf(t, b.y - a.y, a.y);
    o.z = fmaf(t, b.z - a.z, a.z);
    return o;
}

// Each thread: 4 consecutive pixels. Per pixel, 4 gathers into ONE 64B line.
__global__ __launch_bounds__(256) void lut3d_apply_cells_kernel(
    const float* __restrict__ x, const v4u* __restrict__ cells,
    float* __restrict__ out, int n4) {
    constexpr int HW  = 1024 * 1024;
    constexpr int HW4 = HW / 4;

    int t = blockIdx.x * blockDim.x + threadIdx.x;
    if (t >= n4) return;
    int b  = t >> 18;            // t / HW4
    int hw = t & (HW4 - 1);      // t % HW4

    const v4f* xp = reinterpret_cast<const v4f*>(x + (size_t)b * 3 * HW) + hw;
    v4f r4 = __builtin_nontemporal_load(xp);
    v4f g4 = __builtin_nontemporal_load(xp + HW4);
    v4f b4 = __builtin_nontemporal_load(xp + 2 * HW4);

    const float inv_bin = 32.0f / 1.000001f;

    float rd[4], gd[4], bd[4];
    v4u P00[4], P10[4], P01[4], P11[4];

    // Phase 1: indices + issue all gathers (4 per pixel, same 64B line)
#pragma unroll
    for (int k = 0; k < 4; ++k) {
        float rs = r4[k] * inv_bin;
        float gs = g4[k] * inv_bin;
        float bs = b4[k] * inv_bin;
        float rf = floorf(rs), gf = floorf(gs), bf = floorf(bs);
        int rid = (int)rf, gid = (int)gf, bid = (int)bf;
        rd[k] = rs - rf;
        gd[k] = gs - gf;
        bd[k] = bs - bf;

        const v4u* cell = cells + (((size_t)(rid + (gid << 5) + (bid << 10))) << 2);
        P00[k] = cell[0];
        P10[k] = cell[1];
        P01[k] = cell[2];
        P11[k] = cell[3];
    }

    v4f or4, og4, ob4;

    // Phase 2: interpolate
#pragma unroll
    for (int k = 0; k < 4; ++k) {
        f3 a00 = rlerp(P00[k], rd[k]);   // (g=0,b=0) r-interp
        f3 a10 = rlerp(P10[k], rd[k]);   // (g=1,b=0)
        f3 a01 = rlerp(P01[k], rd[k]);   // (g=0,b=1)
        f3 a11 = rlerp(P11[k], rd[k]);   // (g=1,b=1)
        f3 m0  = lerp3(a00, a10, gd[k]);
        f3 m1  = lerp3(a01, a11, gd[k]);
        f3 res = lerp3(m0, m1, bd[k]);
        or4[k] = res.x;
        og4[k] = res.y;
        ob4[k] = res.z;
    }

    v4f* op = reinterpret_cast<v4f*>(out + (size_t)b * 3 * HW) + hw;
    __builtin_nontemporal_store(or4, op);
    __builtin_nontemporal_store(og4, op + HW4);
    __builtin_nontemporal_store(ob4, op + 2 * HW4);
}

// ---------- fallback path (pairs table, 575 KB) if workspace is small ------
__global__ void repack_lut_pairs_kernel(const float* __restrict__ lut,
                                        v4u* __restrict__ pairs) {
    int i = blockIdx.x * blockDim.x + threadIdx.x;
    if (i >= NLUT) return;
    int j = (i + 1 < NLUT) ? i + 1 : i;
    v4u p;
    p.x = pack2h(lut[i], lut[NLUT + i]);
    p.y = pack2h(lut[2 * NLUT + i], 0.0f);
    p.z = pack2h(lut[j], lut[NLUT + j]);
    p.w = pack2h(lut[2 * NLUT + j], 0.0f);
    pairs[i] = p;
}

__global__ __launch_bounds__(256) void lut3d_apply_pairs_kernel(
    const float* __restrict__ x, const v4u* __restrict__ pairs,
    float* __restrict__ out, int n4) {
    constexpr int HW  = 1024 * 1024;
    constexpr int HW4 = HW / 4;

    int t = blockIdx.x * blockDim.x + threadIdx.x;
    if (t >= n4) return;
    int b  = t >> 18;
    int hw = t & (HW4 - 1);

    const v4f* xp = reinterpret_cast<const v4f*>(x + (size_t)b * 3 * HW) + hw;
    v4f r4 = __builtin_nontemporal_load(xp);
    v4f g4 = __builtin_nontemporal_load(xp + HW4);
    v4f b4 = __builtin_nontemporal_load(xp + 2 * HW4);

    const float inv_bin = 32.0f / 1.000001f;
    float rd[4], gd[4], bd[4];
    v4u P00[4], P10[4], P01[4], P11[4];

#pragma unroll
    for (int k = 0; k < 4; ++k) {
        float rs = r4[k] * inv_bin;
        float gs = g4[k] * inv_bin;
        float bs = b4[k] * inv_bin;
        float rf = floorf(rs), gf = floorf(gs), bf = floorf(bs);
        int rid = (int)rf, gid = (int)gf, bid = (int)bf;
        rd[k] = rs - rf; gd[k] = gs - gf; bd[k] = bs - bf;
        int idx = rid + gid * DIM + bid * DIM2;
        P00[k] = pairs[idx];
        P10[k] = pairs[idx + DIM];
        P01[k] = pairs[idx + DIM2];
        P11[k] = pairs[idx + DIM2 + DIM];
    }

    v4f or4, og4, ob4;
#pragma unroll
    for (int k = 0; k < 4; ++k) {
        f3 a00 = rlerp(P00[k], rd[k]);
        f3 a10 = rlerp(P10[k], rd[k]);
        f3 a01 = rlerp(P01[k], rd[k]);
        f3 a11 = rlerp(P11[k], rd[k]);
        f3 m0  = lerp3(a00, a10, gd[k]);
        f3 m1  = lerp3(a01, a11, gd[k]);
        f3 res = lerp3(m0, m1, bd[k]);
        or4[k] = res.x; og4[k] = res.y; ob4[k] = res.z;
    }

    v4f* op = reinterpret_cast<v4f*>(out + (size_t)b * 3 * HW) + hw;
    __builtin_nontemporal_store(or4, op);
    __builtin_nontemporal_store(og4, op + HW4);
    __builtin_nontemporal_store(ob4, op + 2 * HW4);
}

extern "C" void kernel_launch(void* const* d_in, const int* in_sizes, int n_in,
                              void* d_out, int out_size, void* d_ws, size_t ws_size,
                              hipStream_t stream) {
    const float* x   = (const float*)d_in[0];
    const float* lut = (const float*)d_in[1];
    float* out       = (float*)d_out;

    constexpr int B  = 16;
    constexpr int HW = 1024 * 1024;
    const int n4 = B * (HW / 4);               // 4,194,304 threads
    const int blocks = (n4 + 255) / 256;       // 16384 blocks

    const size_t cells_bytes = (size_t)NCELL * 64;          // 2 MB
    const size_t pairs_bytes = (size_t)NLUT * sizeof(v4u);  // 575 KB

    if (ws_size >= cells_bytes) {
        v4u* cells = (v4u*)d_ws;
        repack_cells_kernel<<<(NCELL + 255) / 256, 256, 0, stream>>>(lut, cells);
        lut3d_apply_cells_kernel<<<blocks, 256, 0, stream>>>(x, cells, out, n4);
    } else {
        v4u* pairs = (v4u*)d_ws;
        repack_lut_pairs_kernel<<<(NLUT + 255) / 256, 256, 0, stream>>>(lut, pairs);
        lut3d_apply_pairs_kernel<<<blocks, 256, 0, stream>>>(x, pairs, out, n4);
    }
}

// Round 5
// 102.214 us; speedup vs baseline: 3.2160x; 2.2859x over previous
//
#include <hip/hip_runtime.h>

#define DIM 33
#define DIM2 (DIM * DIM)
#define NLUT (DIM * DIM * DIM)     // 35937 entries

typedef float v4f __attribute__((ext_vector_type(4)));

// ---- Quantize planar f32 LUT to one u32 per entry: r|g<<10|b<<20 (10b each)
__device__ __forceinline__ unsigned q10(float v) {
    float c = fminf(fmaxf(v, 0.0f), 1.0f);
    return (unsigned)(fmaf(c, 1023.0f, 0.5f));
}

__global__ void repack_q10_kernel(const float* __restrict__ lut,
                                  unsigned* __restrict__ lutq) {
    int i = blockIdx.x * blockDim.x + threadIdx.x;
    if (i >= NLUT) return;
    unsigned r = q10(lut[i]);
    unsigned g = q10(lut[NLUT + i]);
    unsigned b = q10(lut[2 * NLUT + i]);
    lutq[i] = r | (g << 10) | (b << 20);
}

struct f3 { float x, y, z; };

__device__ __forceinline__ f3 dec(unsigned u) {
    f3 o;
    o.x = (float)(u & 1023u);
    o.y = (float)((u >> 10) & 1023u);
    o.z = (float)((u >> 20) & 1023u);
    return o;
}

__device__ __forceinline__ f3 lerp3(const f3 a, const f3 b, const float t) {
    f3 o;
    o.x = fmaf(t, b.x - a.x, a.x);
    o.y = fmaf(t, b.y - a.y, a.y);
    o.z = fmaf(t, b.z - a.z, a.z);
    return o;
}

// One 1024-thread block per CU; whole LUT staged in LDS (143.7 KB).
// Each thread: 16 grid-stride iterations x 4 pixels, x-prefetch depth 1.
__global__ __launch_bounds__(1024) void lut3d_apply_lds_kernel(
    const float* __restrict__ x, const unsigned* __restrict__ lutq,
    float* __restrict__ out) {
    constexpr int HW    = 1024 * 1024;
    constexpr int HW4   = HW / 4;
    constexpr int ITERS = 16;

    __shared__ unsigned ls[NLUT];   // 143748 B (gfx950: 160 KiB LDS/CU)

    // Stage LUT into LDS (coalesced)
    for (int i = threadIdx.x; i < NLUT; i += 1024)
        ls[i] = lutq[i];
    __syncthreads();

    const float inv_bin = 32.0f / 1.000001f;
    const int g0 = blockIdx.x * (ITERS * 1024) + threadIdx.x;

    v4f cr, cg, cb;
    {
        int g = g0;
        int b = g >> 18, hw = g & (HW4 - 1);
        const v4f* xp = reinterpret_cast<const v4f*>(x + (size_t)b * 3 * HW) + hw;
        cr = __builtin_nontemporal_load(xp);
        cg = __builtin_nontemporal_load(xp + HW4);
        cb = __builtin_nontemporal_load(xp + 2 * HW4);
    }

    for (int it = 0; it < ITERS; ++it) {
        // Prefetch next iteration's pixels
        v4f nr, ng, nb;
        if (it + 1 < ITERS) {
            int g = g0 + (it + 1) * 1024;
            int b = g >> 18, hw = g & (HW4 - 1);
            const v4f* xp = reinterpret_cast<const v4f*>(x + (size_t)b * 3 * HW) + hw;
            nr = __builtin_nontemporal_load(xp);
            ng = __builtin_nontemporal_load(xp + HW4);
            nb = __builtin_nontemporal_load(xp + 2 * HW4);
        }

        float rd[4], gd[4], bd[4];
        unsigned C[4][8];

        // Phase 1: indices + all 32 LDS gathers (pairs merge to ds_read2_b32)
#pragma unroll
        for (int k = 0; k < 4; ++k) {
            float rs = cr[k] * inv_bin;
            float gs = cg[k] * inv_bin;
            float bs = cb[k] * inv_bin;
            float rf = floorf(rs), gf = floorf(gs), bf = floorf(bs);
            int rid = (int)rf, gid = (int)gf, bid = (int)bf;
            rd[k] = rs - rf;
            gd[k] = gs - gf;
            bd[k] = bs - bf;

            int idx = rid + gid * DIM + bid * DIM2;
            C[k][0] = ls[idx];
            C[k][1] = ls[idx + 1];
            C[k][2] = ls[idx + DIM];
            C[k][3] = ls[idx + DIM + 1];
            C[k][4] = ls[idx + DIM2];
            C[k][5] = ls[idx + DIM2 + 1];
            C[k][6] = ls[idx + DIM2 + DIM];
            C[k][7] = ls[idx + DIM2 + DIM + 1];
        }

        v4f or4, og4, ob4;

        // Phase 2: decode + trilinear (scale by 1/1023 once at the end)
#pragma unroll
        for (int k = 0; k < 4; ++k) {
            f3 a00 = lerp3(dec(C[k][0]), dec(C[k][1]), rd[k]);
            f3 a10 = lerp3(dec(C[k][2]), dec(C[k][3]), rd[k]);
            f3 a01 = lerp3(dec(C[k][4]), dec(C[k][5]), rd[k]);
            f3 a11 = lerp3(dec(C[k][6]), dec(C[k][7]), rd[k]);
            f3 m0  = lerp3(a00, a10, gd[k]);
            f3 m1  = lerp3(a01, a11, gd[k]);
            f3 res = lerp3(m0, m1, bd[k]);
            or4[k] = res.x * (1.0f / 1023.0f);
            og4[k] = res.y * (1.0f / 1023.0f);
            ob4[k] = res.z * (1.0f / 1023.0f);
        }

        {
            int g = g0 + it * 1024;
            int b = g >> 18, hw = g & (HW4 - 1);
            v4f* op = reinterpret_cast<v4f*>(out + (size_t)b * 3 * HW) + hw;
            __builtin_nontemporal_store(or4, op);
            __builtin_nontemporal_store(og4, op + HW4);
            __builtin_nontemporal_store(ob4, op + 2 * HW4);
        }

        cr = nr; cg = ng; cb = nb;
    }
}

extern "C" void kernel_launch(void* const* d_in, const int* in_sizes, int n_in,
                              void* d_out, int out_size, void* d_ws, size_t ws_size,
                              hipStream_t stream) {
    const float* x   = (const float*)d_in[0];
    const float* lut = (const float*)d_in[1];
    float* out       = (float*)d_out;

    unsigned* lutq = (unsigned*)d_ws;   // 143.7 KB scratch

    repack_q10_kernel<<<(NLUT + 255) / 256, 256, 0, stream>>>(lut, lutq);
    // 256 blocks x 1024 threads: one block per CU, 16 iters x 4 px per thread
    lut3d_apply_lds_kernel<<<256, 1024, 0, stream>>>(x, lutq, out);
}

// Round 7
// 86.646 us; speedup vs baseline: 3.7938x; 1.1797x over previous
//
#include <hip/hip_runtime.h>

#define DIM 33
#define DIM2 (DIM * DIM)
#define NLUT (DIM * DIM * DIM)     // 35937 entries
#define NLUT_PAD 35940             // padded to multiple of 4 for uint4 staging

typedef float        v4f __attribute__((ext_vector_type(4)));
typedef unsigned int v4u __attribute__((ext_vector_type(4)));

// ---- Quantize planar f32 LUT to RGBA8: r | g<<8 | b<<16 ----
__device__ __forceinline__ unsigned q8(float v) {
    float c = fminf(fmaxf(v, 0.0f), 1.0f);
    return (unsigned)(fmaf(c, 255.0f, 0.5f));
}

__global__ void repack_q8_kernel(const float* __restrict__ lut,
                                 unsigned* __restrict__ lutq) {
    int i = blockIdx.x * blockDim.x + threadIdx.x;
    if (i >= NLUT_PAD) return;
    int j = (i < NLUT) ? i : NLUT - 1;      // pad entries replicate last
    unsigned r = q8(lut[j]);
    unsigned g = q8(lut[NLUT + j]);
    unsigned b = q8(lut[2 * NLUT + j]);
    lutq[i] = r | (g << 8) | (b << 16);
}

struct f3 { float x, y, z; };

// LLVM pattern-matches these to v_cvt_f32_ubyte{0,1,2}
__device__ __forceinline__ f3 dec(unsigned u) {
    f3 o;
    o.x = (float)(u & 0xffu);
    o.y = (float)((u >> 8) & 0xffu);
    o.z = (float)((u >> 16) & 0xffu);
    return o;
}

__device__ __forceinline__ f3 lerp3(const f3 a, const f3 b, const float t) {
    f3 o;
    o.x = fmaf(t, b.x - a.x, a.x);
    o.y = fmaf(t, b.y - a.y, a.y);
    o.z = fmaf(t, b.z - a.z, a.z);
    return o;
}

// 512 blocks x 1024 threads; whole LUT (RGBA8, 143.8 KB) in LDS.
// Each thread: 8 iterations x 4 pixels, x-prefetch depth 2.
__global__ __launch_bounds__(1024) void lut3d_apply_lds_kernel(
    const float* __restrict__ x, const unsigned* __restrict__ lutq,
    float* __restrict__ out) {
    constexpr int HW    = 1024 * 1024;
    constexpr int HW4   = HW / 4;
    constexpr int ITERS = 8;

    __shared__ unsigned ls[NLUT_PAD];   // 143760 B (gfx950: 160 KiB LDS/CU)

    // Stage LUT into LDS, vectorized (uint4): 8985 vec4 slots
    {
        const v4u* src = reinterpret_cast<const v4u*>(lutq);
        v4u* dst = reinterpret_cast<v4u*>(ls);
        for (int i = threadIdx.x; i < NLUT_PAD / 4; i += 1024)
            dst[i] = src[i];
    }
    __syncthreads();

    const float inv_bin = 32.0f / 1.000001f;
    const int g0 = blockIdx.x * (ITERS * 1024) + threadIdx.x;

    v4f pr[3][3];   // [slot][plane] rolling prefetch buffers, depth 2
#pragma unroll
    for (int p = 0; p < 2; ++p) {
        int g = g0 + p * 1024;
        int b = g >> 18, hw = g & (HW4 - 1);
        const v4f* xp = reinterpret_cast<const v4f*>(x + (size_t)b * 3 * HW) + hw;
        pr[p][0] = __builtin_nontemporal_load(xp);
        pr[p][1] = __builtin_nontemporal_load(xp + HW4);
        pr[p][2] = __builtin_nontemporal_load(xp + 2 * HW4);
    }

#pragma unroll
    for (int it = 0; it < ITERS; ++it) {
        const int s0 = it % 3, s2 = (it + 2) % 3;
        // Prefetch iter+2
        if (it + 2 < ITERS) {
            int g = g0 + (it + 2) * 1024;
            int b = g >> 18, hw = g & (HW4 - 1);
            const v4f* xp = reinterpret_cast<const v4f*>(x + (size_t)b * 3 * HW) + hw;
            pr[s2][0] = __builtin_nontemporal_load(xp);
            pr[s2][1] = __builtin_nontemporal_load(xp + HW4);
            pr[s2][2] = __builtin_nontemporal_load(xp + 2 * HW4);
        }

        v4f cr = pr[s0][0], cg = pr[s0][1], cb = pr[s0][2];

        float rd[4], gd[4], bd[4];
        unsigned C[4][8];

        // Phase 1: indices (float-domain) + all LDS gathers
#pragma unroll
        for (int k = 0; k < 4; ++k) {
            float rs = cr[k] * inv_bin;
            float gs = cg[k] * inv_bin;
            float bs = cb[k] * inv_bin;
            float rf = floorf(rs), gf = floorf(gs), bf = floorf(bs);
            rd[k] = rs - rf;
            gd[k] = gs - gf;
            bd[k] = bs - bf;

            // idx = rf + 33*gf + 1089*bf  (exact in f32, < 2^24)
            float idxf = fmaf(1089.0f, bf, fmaf(33.0f, gf, rf));
            int idx = (int)idxf;

            C[k][0] = ls[idx];
            C[k][1] = ls[idx + 1];
            C[k][2] = ls[idx + DIM];
            C[k][3] = ls[idx + DIM + 1];
            C[k][4] = ls[idx + DIM2];
            C[k][5] = ls[idx + DIM2 + 1];
            C[k][6] = ls[idx + DIM2 + DIM];
            C[k][7] = ls[idx + DIM2 + DIM + 1];
        }

        v4f or4, og4, ob4;

        // Phase 2: ubyte decode + trilinear; scale by 1/255 at the end
#pragma unroll
        for (int k = 0; k < 4; ++k) {
            f3 a00 = lerp3(dec(C[k][0]), dec(C[k][1]), rd[k]);
            f3 a10 = lerp3(dec(C[k][2]), dec(C[k][3]), rd[k]);
            f3 a01 = lerp3(dec(C[k][4]), dec(C[k][5]), rd[k]);
            f3 a11 = lerp3(dec(C[k][6]), dec(C[k][7]), rd[k]);
            f3 m0  = lerp3(a00, a10, gd[k]);
            f3 m1  = lerp3(a01, a11, gd[k]);
            f3 res = lerp3(m0, m1, bd[k]);
            or4[k] = res.x * (1.0f / 255.0f);
            og4[k] = res.y * (1.0f / 255.0f);
            ob4[k] = res.z * (1.0f / 255.0f);
        }

        {
            int g = g0 + it * 1024;
            int b = g >> 18, hw = g & (HW4 - 1);
            v4f* op = reinterpret_cast<v4f*>(out + (size_t)b * 3 * HW) + hw;
            __builtin_nontemporal_store(or4, op);
            __builtin_nontemporal_store(og4, op + HW4);
            __builtin_nontemporal_store(ob4, op + 2 * HW4);
        }
    }
}

extern "C" void kernel_launch(void* const* d_in, const int* in_sizes, int n_in,
                              void* d_out, int out_size, void* d_ws, size_t ws_size,
                              hipStream_t stream) {
    const float* x   = (const float*)d_in[0];
    const float* lut = (const float*)d_in[1];
    float* out       = (float*)d_out;

    unsigned* lutq = (unsigned*)d_ws;   // 143.8 KB scratch

    repack_q8_kernel<<<(NLUT_PAD + 255) / 256, 256, 0, stream>>>(lut, lutq);
    // 512 blocks x 1024 threads: 8 iters x 4 px per thread
    lut3d_apply_lds_kernel<<<512, 1024, 0, stream>>>(x, lutq, out);
}